// Round 5
// baseline (436.188 us; speedup 1.0000x reference)
//
#include <hip/hip_runtime.h>
#include <hip/hip_bf16.h>

#define B_ 4096
#define N_ 30
#define D_ 512
#define H_ 4
#define M_ (B_*N_)      // 122880 tokens
#define PE_ROWS 31

typedef unsigned short u16;
typedef __attribute__((ext_vector_type(8))) short bf16x8;
typedef __attribute__((ext_vector_type(4))) float f32x4;

__device__ __forceinline__ float bf2f(u16 s) { return __uint_as_float(((unsigned)s) << 16); }
__device__ __forceinline__ u16 f2bf(float f) {
  __hip_bfloat16 h = __float2bfloat16(f);
  return *reinterpret_cast<u16*>(&h);
}

// fast tanh: 1 - 2/(exp(2x)+1); exp->v_exp_f32, rcp->v_rcp_f32 (~1e-7 rel err)
__device__ __forceinline__ float ftanh(float x) {
  float e = __expf(2.f * x);
  return 1.f - 2.f * __builtin_amdgcn_rcpf(e + 1.f);
}

// full-wave (64-lane) sum / max
__device__ __forceinline__ float wsum(float v) {
  #pragma unroll
  for (int m = 32; m >= 1; m >>= 1) v += __shfl_xor(v, m);
  return v;
}
__device__ __forceinline__ float wmax(float v) {
  #pragma unroll
  for (int m = 32; m >= 1; m >>= 1) v = fmaxf(v, __shfl_xor(v, m));
  return v;
}

// block-wide sum over 512 threads (8 waves of 64)
__device__ __forceinline__ float bsum512(float v, float* red) {
  int lane = threadIdx.x & 63;
  int w = threadIdx.x >> 6;
  #pragma unroll
  for (int m = 32; m >= 1; m >>= 1) v += __shfl_xor(v, m);
  if (lane == 0) red[w] = v;
  __syncthreads();
  if (threadIdx.x < 64) {
    float t = (lane < 8) ? red[lane] : 0.0f;
    #pragma unroll
    for (int m = 4; m >= 1; m >>= 1) t += __shfl_xor(t, m);
    if (lane == 0) red[0] = t;
  }
  __syncthreads();
  float r = red[0];
  __syncthreads();
  return r;
}

// K1: wave-per-token. Each of 8 waves owns tokens n = wid+8t (t<4); a token's
// 512-elem row lives as 8 floats/lane. All row reductions are intra-wave
// shfl_xor. Single __syncthreads for the cross-wave mp/mpx pool reduce.
__global__ __launch_bounds__(512) void k1_prep(
    const float* __restrict__ x, const int* __restrict__ order,
    const float* __restrict__ ndocs, const float* __restrict__ dw,
    const float* __restrict__ pe, const float* __restrict__ g1,
    const float* __restrict__ bln1,
    u16* __restrict__ x1bf, float* __restrict__ mp, float* __restrict__ mpx,
    float* __restrict__ cosb) {
  __shared__ float lds_mp[8*512];
  __shared__ float lds_mpx[8*512];
  __shared__ float xps[32];
  int b = blockIdx.x;
  int tid = threadIdx.x;
  int wid = tid >> 6, lane = tid & 63;
  int d0 = lane * 8;
  float g[8], bl[8];
  *(float4*)&g[0]  = *(const float4*)&g1[d0];
  *(float4*)&g[4]  = *(const float4*)&g1[d0+4];
  *(float4*)&bl[0] = *(const float4*)&bln1[d0];
  *(float4*)&bl[4] = *(const float4*)&bln1[d0+4];
  float xp_reg[4][8];
  float accmp[8] = {0,0,0,0,0,0,0,0}, accmpx[8] = {0,0,0,0,0,0,0,0};
  #pragma unroll
  for (int t = 0; t < 4; ++t) {
    int n = wid + 8*t;
    if (n < N_) {
      int tok = b*N_ + n;
      float v[8];
      *(float4*)&v[0] = *(const float4*)&x[(size_t)tok*D_ + d0];
      *(float4*)&v[4] = *(const float4*)&x[(size_t)tok*D_ + d0 + 4];
      float ss = 0.f;
      #pragma unroll
      for (int i = 0; i < 8; ++i) ss += v[i]*v[i];
      ss = wsum(ss);
      float inv = 1.f / fmaxf(sqrtf(ss), 1e-8f);
      float mu = 0.f;
      #pragma unroll
      for (int i = 0; i < 8; ++i) { v[i] *= inv; mu += v[i]; }
      mu = wsum(mu) * (1.f/D_);
      float m2 = ss*inv*inv*(1.f/D_);   // mean(xn^2), exact
      float rs = 1.f / sqrtf(m2 - mu*mu + 1e-5f);
      int o = order[tok];
      float p8[8];
      *(float4*)&p8[0] = *(const float4*)&pe[(size_t)o*D_ + d0];
      *(float4*)&p8[4] = *(const float4*)&pe[(size_t)o*D_ + d0 + 4];
      float wv = dw[tok];
      float sq = 0.f;
      bf16x8 xb;
      #pragma unroll
      for (int i = 0; i < 8; ++i) {
        float x1v = g[i]*((v[i]-mu)*rs) + bl[i];
        xb[i] = (short)f2bf(x1v);
        float xpv = x1v + p8[i];
        xp_reg[t][i] = xpv;
        accmp[i]  += wv*xpv;
        accmpx[i] += wv*x1v;
        sq += xpv*xpv;
      }
      *(bf16x8*)&x1bf[(size_t)tok*D_ + d0] = xb;
      sq = wsum(sq);
      if (lane == 0) xps[n] = sq;
    }
  }
  #pragma unroll
  for (int i = 0; i < 8; i += 4) {
    *(float4*)&lds_mp[wid*512 + d0 + i]  = *(float4*)&accmp[i];
    *(float4*)&lds_mpx[wid*512 + d0 + i] = *(float4*)&accmpx[i];
  }
  __syncthreads();
  float invnd = 1.f / ndocs[b];
  float mpv[8] = {0,0,0,0,0,0,0,0}, mpxv[8] = {0,0,0,0,0,0,0,0};
  #pragma unroll
  for (int w = 0; w < 8; ++w) {
    #pragma unroll
    for (int i = 0; i < 8; i += 4) {
      float4 a = *(float4*)&lds_mp[w*512 + d0 + i];
      mpv[i+0] += a.x; mpv[i+1] += a.y; mpv[i+2] += a.z; mpv[i+3] += a.w;
      float4 c = *(float4*)&lds_mpx[w*512 + d0 + i];
      mpxv[i+0] += c.x; mpxv[i+1] += c.y; mpxv[i+2] += c.z; mpxv[i+3] += c.w;
    }
  }
  #pragma unroll
  for (int i = 0; i < 8; ++i) { mpv[i] *= invnd; mpxv[i] *= invnd; }
  if (wid == 0) {
    #pragma unroll
    for (int i = 0; i < 8; i += 4)
      *(float4*)&mp[(size_t)b*D_ + d0 + i] = *(float4*)&mpv[i];
  }
  if (wid == 1) {
    #pragma unroll
    for (int i = 0; i < 8; i += 4)
      *(float4*)&mpx[(size_t)b*D_ + d0 + i] = *(float4*)&mpxv[i];
  }
  float mn = 0.f;
  #pragma unroll
  for (int i = 0; i < 8; ++i) mn += mpv[i]*mpv[i];
  float mpn = sqrtf(wsum(mn));
  #pragma unroll
  for (int t = 0; t < 4; ++t) {
    int n = wid + 8*t;
    if (n < N_) {
      float dot = 0.f;
      #pragma unroll
      for (int i = 0; i < 8; ++i) dot += mpv[i]*xp_reg[t][i];
      dot = wsum(dot);
      if (lane == 0)
        cosb[b*N_ + n] = dot / fmaxf(mpn * sqrtf(xps[n]), 1e-8f);
    }
  }
}

// peW[p][j] = pos_emb[p] @ W_top   (31 x 512)
__global__ __launch_bounds__(512) void k_pew(
    const float* __restrict__ pe, const float* __restrict__ w1,
    float* __restrict__ peW) {
  int p = blockIdx.x, j = threadIdx.x;
  float acc = 0.f;
  for (int dd = 0; dd < D_; ++dd) acc += pe[p*D_ + dd] * w1[(size_t)dd*D_ + j];
  peW[p*D_ + j] = acc;
}

// mpW[b][j] = mp[b] @ W_mid + fc1_b1[j]   (8 batches per block)
__global__ __launch_bounds__(512) void k2_mpw(
    const float* __restrict__ mp, const float* __restrict__ w1,
    const float* __restrict__ b1, float* __restrict__ mpW) {
  __shared__ float mps[8][D_];
  int j = threadIdx.x;
  int b0 = blockIdx.x * 8;
  #pragma unroll
  for (int r = 0; r < 8; ++r) mps[r][j] = mp[(size_t)(b0+r)*D_ + j];
  __syncthreads();
  float bv = b1[j];
  float acc[8] = {bv,bv,bv,bv,bv,bv,bv,bv};
  for (int dd = 0; dd < D_; ++dd) {
    float wv = w1[(size_t)(D_+dd)*D_ + j];
    #pragma unroll
    for (int r = 0; r < 8; ++r) acc[r] += mps[r][dd] * wv;
  }
  #pragma unroll
  for (int r = 0; r < 8; ++r) mpW[(size_t)(b0+r)*D_ + j] = acc[r];
}

// Tiled transpose+convert: out[j][k] = bf16(in[k][j]). 64x64 tiles, 256 thr.
__global__ __launch_bounds__(256) void k_tcvt(
    const float* __restrict__ in, u16* __restrict__ out, int Kdim, int Jdim) {
  __shared__ float tile[64][65];
  int k0 = blockIdx.x * 64, j0 = blockIdx.y * 64;
  int t = threadIdx.x;
  int tr = t >> 4, tc4 = (t & 15) * 4;
  #pragma unroll
  for (int i = 0; i < 4; ++i) {
    int k = k0 + tr + i*16;
    float4 v = *(const float4*)&in[(size_t)k*Jdim + j0 + tc4];
    tile[tr + i*16][tc4+0] = v.x;
    tile[tr + i*16][tc4+1] = v.y;
    tile[tr + i*16][tc4+2] = v.z;
    tile[tr + i*16][tc4+3] = v.w;
  }
  __syncthreads();
  #pragma unroll
  for (int i = 0; i < 4; ++i) {
    int j = tr + i*16;
    uint2 u;
    u.x = (unsigned)f2bf(tile[tc4+0][j]) | ((unsigned)f2bf(tile[tc4+1][j]) << 16);
    u.y = (unsigned)f2bf(tile[tc4+2][j]) | ((unsigned)f2bf(tile[tc4+3][j]) << 16);
    *(uint2*)&out[(size_t)(j0+j)*Kdim + k0 + tc4] = u;
  }
}

// K4 v4: MFMA bf16 GEMM, BM=128, BN=256 (split-N over 2 blocks), BK=32.
// 8 waves 2(M)x4(N); wave tile 64x64, acc 4x4 f32x4 = 64 regs -> 2 blocks/CU.
// Additive terms in acc init; epilogue tanh+w2-dot -> partial Z per N-half.
__global__ __launch_bounds__(512) void k4_fc1(
    const u16* __restrict__ x1bf, const u16* __restrict__ w1T,
    const float* __restrict__ w1, const float* __restrict__ w2,
    const int* __restrict__ order, const float* __restrict__ cosb,
    const float* __restrict__ mpW, const float* __restrict__ peW,
    float* __restrict__ Zp) {
  __shared__ __align__(16) char smem[(128*40 + 256*40)*2];   // 30720 B
  u16* As = (u16*)smem;                  // [128][40]
  u16* Bs = (u16*)smem + 128*40;         // [256][40]
  float* zred = (float*)smem;            // epilogue alias: [4][128][4] = 8KB
  int tid = threadIdx.x;
  int row0 = blockIdx.x * 128;
  int col0 = blockIdx.y * 256;
  int wid = tid >> 6, lane = tid & 63;
  int wm = wid >> 2, wn = wid & 3;
  int lr = lane & 15, lk = lane >> 4;
  int sra = tid >> 2, ska = (tid & 3) << 3;
  // per-lane w2 rows and cos-coefficient (registers)
  float w2r[4][4], wl[4];
  #pragma unroll
  for (int nf = 0; nf < 4; ++nf) {
    int jl = col0 + wn*64 + nf*16 + lr;
    *(float4*)w2r[nf] = *(const float4*)&w2[jl*4];
    wl[nf] = w1[(size_t)1024*D_ + jl];
  }
  // acc init = mpW[bidx][jl] + peW[o][jl] + cs*wl
  f32x4 acc[4][4];
  #pragma unroll
  for (int mf = 0; mf < 4; ++mf) {
    #pragma unroll
    for (int r = 0; r < 4; ++r) {
      int m = row0 + wm*64 + mf*16 + lk*4 + r;
      int bidx = m / N_;
      int o = order[m];
      float cs = cosb[m];
      #pragma unroll
      for (int nf = 0; nf < 4; ++nf) {
        int jl = col0 + wn*64 + nf*16 + lr;
        acc[mf][nf][r] = mpW[(size_t)bidx*D_ + jl] + peW[o*D_ + jl] + cs*wl[nf];
      }
    }
  }
  bf16x8 ra, rb[2];
  ra = *(const bf16x8*)&x1bf[(size_t)(row0 + sra)*D_ + ska];
  #pragma unroll
  for (int p = 0; p < 2; ++p) {
    int idx = p*512 + tid;
    int c = idx >> 2, kc = (idx & 3) << 3;
    rb[p] = *(const bf16x8*)&w1T[(size_t)(col0 + c)*D_ + kc];
  }
  for (int k0 = 0; k0 < D_; k0 += 32) {
    __syncthreads();
    *(bf16x8*)&As[sra*40 + ska] = ra;
    #pragma unroll
    for (int p = 0; p < 2; ++p) {
      int idx = p*512 + tid;
      int c = idx >> 2, kc = (idx & 3) << 3;
      *(bf16x8*)&Bs[c*40 + kc] = rb[p];
    }
    __syncthreads();
    if (k0 + 32 < D_) {
      ra = *(const bf16x8*)&x1bf[(size_t)(row0 + sra)*D_ + k0 + 32 + ska];
      #pragma unroll
      for (int p = 0; p < 2; ++p) {
        int idx = p*512 + tid;
        int c = idx >> 2, kc = (idx & 3) << 3;
        rb[p] = *(const bf16x8*)&w1T[(size_t)(col0 + c)*D_ + k0 + 32 + kc];
      }
    }
    bf16x8 a[4];
    #pragma unroll
    for (int mf = 0; mf < 4; ++mf)
      a[mf] = *(const bf16x8*)&As[(wm*64 + mf*16 + lr)*40 + lk*8];
    #pragma unroll
    for (int nf = 0; nf < 4; ++nf) {
      bf16x8 bfr = *(const bf16x8*)&Bs[(wn*64 + nf*16 + lr)*40 + lk*8];
      #pragma unroll
      for (int mf = 0; mf < 4; ++mf)
        acc[mf][nf] = __builtin_amdgcn_mfma_f32_16x16x32_bf16(a[mf], bfr, acc[mf][nf], 0, 0, 0);
    }
  }
  __syncthreads();   // frag reads done -> safe to alias zred
  #pragma unroll
  for (int mf = 0; mf < 4; ++mf) {
    #pragma unroll
    for (int r = 0; r < 4; ++r) {
      int rowt = wm*64 + mf*16 + lk*4 + r;
      float z0=0.f, z1=0.f, z2=0.f, z3=0.f;
      #pragma unroll
      for (int nf = 0; nf < 4; ++nf) {
        float t = ftanh(acc[mf][nf][r]);
        z0 += t * w2r[nf][0]; z1 += t * w2r[nf][1];
        z2 += t * w2r[nf][2]; z3 += t * w2r[nf][3];
      }
      #pragma unroll
      for (int msk = 1; msk <= 8; msk <<= 1) {
        z0 += __shfl_xor(z0, msk); z1 += __shfl_xor(z1, msk);
        z2 += __shfl_xor(z2, msk); z3 += __shfl_xor(z3, msk);
      }
      if (lr == 0)
        *(float4*)&zred[(wn*128 + rowt)*4] = make_float4(z0, z1, z2, z3);
    }
  }
  __syncthreads();
  if (tid < 128) {
    float4 s0 = *(float4*)&zred[(0*128 + tid)*4];
    float4 s1 = *(float4*)&zred[(1*128 + tid)*4];
    float4 s2 = *(float4*)&zred[(2*128 + tid)*4];
    float4 s3 = *(float4*)&zred[(3*128 + tid)*4];
    float4 s;
    s.x = s0.x+s1.x+s2.x+s3.x; s.y = s0.y+s1.y+s2.y+s3.y;
    s.z = s0.z+s1.z+s2.z+s3.z; s.w = s0.w+s1.w+s2.w+s3.w;
    *(float4*)&Zp[((size_t)blockIdx.y*M_ + row0 + tid)*4] = s;
  }
}

// K5 v2: wave-per-batch. Softmax fully in-wave (shfl); pooling with bf16x8
// vector loads; LN2; emits Hh2 bf16 + head-mean (f32). One barrier.
__global__ __launch_bounds__(512) void k5_attn(
    const float* __restrict__ Zp, const float* __restrict__ b2,
    const unsigned char* __restrict__ amask, const u16* __restrict__ x1bf,
    const float* __restrict__ mpx, const float* __restrict__ g2,
    const float* __restrict__ bln2, u16* __restrict__ Hh2bf,
    float* __restrict__ hmean) {
  __shared__ float abuf[8][120];   // per-wave A in [n][h]-flat layout
  int tid = threadIdx.x;
  int wid = tid >> 6, lane = tid & 63;
  int b = blockIdx.x*8 + wid;
  bool act = lane < N_;
  int tok = b*N_ + (act ? lane : 0);
  float zz[4] = {-INFINITY, -INFINITY, -INFINITY, -INFINITY};
  if (act) {
    float4 z0 = *(const float4*)&Zp[(size_t)tok*4];
    float4 z1 = *(const float4*)&Zp[((size_t)M_ + tok)*4];
    float4 bv = *(const float4*)b2;
    zz[0] = z0.x + z1.x + bv.x; zz[1] = z0.y + z1.y + bv.y;
    zz[2] = z0.z + z1.z + bv.z; zz[3] = z0.w + z1.w + bv.w;
    if (amask[tok]) { zz[0]=zz[1]=zz[2]=zz[3]=-INFINITY; }
  }
  float p[4];
  #pragma unroll
  for (int h = 0; h < 4; ++h) {
    float mx = wmax(zz[h]);
    float e = act ? __expf(zz[h] - mx) : 0.f;
    float s = wsum(e);
    p[h] = e / s;
  }
  if (act) *(float4*)&abuf[wid][lane*4] = make_float4(p[0], p[1], p[2], p[3]);
  __syncthreads();
  // pooling: reshaped A_h[i][j] = abuf.flat[i*30+j]
  float hv[4][8] = {};
  const u16* xr = &x1bf[(size_t)b*N_*D_ + lane*8];
  for (int j = 0; j < N_; ++j) {
    bf16x8 xb = *(const bf16x8*)(xr + (size_t)j*D_);
    float xv[8];
    #pragma unroll
    for (int e = 0; e < 8; ++e) xv[e] = bf2f((u16)xb[e]);
    #pragma unroll
    for (int i = 0; i < 4; ++i) {
      float a = abuf[wid][i*N_ + j];
      #pragma unroll
      for (int e = 0; e < 8; ++e) hv[i][e] += a * xv[e];
    }
  }
  float mpxv[8];
  *(float4*)&mpxv[0] = *(const float4*)&mpx[(size_t)b*D_ + lane*8];
  *(float4*)&mpxv[4] = *(const float4*)&mpx[(size_t)b*D_ + lane*8 + 4];
  float s1 = 0.f, s2 = 0.f;
  #pragma unroll
  for (int i = 0; i < 4; ++i)
    #pragma unroll
    for (int e = 0; e < 8; ++e) {
      hv[i][e] += mpxv[e];
      s1 += hv[i][e];
      s2 += hv[i][e]*hv[i][e];
    }
  s1 = wsum(s1); s2 = wsum(s2);
  float mu = s1 * (1.f/2048.f);
  float var = s2 * (1.f/2048.f) - mu*mu;
  float rs = 1.f / sqrtf(var + 1e-5f);
  float hm[8] = {0,0,0,0,0,0,0,0};
  #pragma unroll
  for (int i = 0; i < 4; ++i) {
    int idx = i*D_ + lane*8;
    float gg[8], bb[8];
    *(float4*)&gg[0] = *(const float4*)&g2[idx];
    *(float4*)&gg[4] = *(const float4*)&g2[idx+4];
    *(float4*)&bb[0] = *(const float4*)&bln2[idx];
    *(float4*)&bb[4] = *(const float4*)&bln2[idx+4];
    bf16x8 ob;
    #pragma unroll
    for (int e = 0; e < 8; ++e) {
      float v = gg[e]*((hv[i][e]-mu)*rs) + bb[e];
      hm[e] += v;
      ob[e] = (short)f2bf(v);
    }
    *(bf16x8*)&Hh2bf[(size_t)b*2048 + idx] = ob;
  }
  #pragma unroll
  for (int e = 0; e < 8; ++e) hm[e] *= 0.25f;
  *(float4*)&hmean[(size_t)b*D_ + lane*8]     = *(float4*)&hm[0];
  *(float4*)&hmean[(size_t)b*D_ + lane*8 + 4] = *(float4*)&hm[4];
}

// K6 v2: MFMA bf16 fc2 GEMM. BM=64, BN=64, BK=128; 4 waves 2x2 (wave 32x32);
// grid (64,8)=512 blocks -> 2+ blocks/CU.
__global__ __launch_bounds__(256) void k6_fc2(
    const u16* __restrict__ Hh2bf, const u16* __restrict__ fwT,
    const float* __restrict__ fb, float* __restrict__ pred0) {
  __shared__ u16 As[64*136];     // [row][k], stride 136
  __shared__ u16 Bs[64*136];     // [col][k]
  int tid = threadIdx.x;
  int row0 = blockIdx.x * 64, col0 = blockIdx.y * 64;
  int wid = tid >> 6, lane = tid & 63;
  int wm = wid >> 1, wn = wid & 1;
  int lr = lane & 15, lk = lane >> 4;
  f32x4 acc[2][2] = {};
  bf16x8 raa[4], rbb[4];
  #pragma unroll
  for (int p = 0; p < 4; ++p) {
    int idx = p*256 + tid;
    int r = idx >> 4, kc = (idx & 15) << 3;
    raa[p] = *(const bf16x8*)&Hh2bf[(size_t)(row0 + r)*2048 + kc];
    rbb[p] = *(const bf16x8*)&fwT[(size_t)(col0 + r)*2048 + kc];
  }
  for (int k0 = 0; k0 < 2048; k0 += 128) {
    __syncthreads();
    #pragma unroll
    for (int p = 0; p < 4; ++p) {
      int idx = p*256 + tid;
      int r = idx >> 4, kc = (idx & 15) << 3;
      *(bf16x8*)&As[r*136 + kc] = raa[p];
      *(bf16x8*)&Bs[r*136 + kc] = rbb[p];
    }
    __syncthreads();
    if (k0 + 128 < 2048) {
      #pragma unroll
      for (int p = 0; p < 4; ++p) {
        int idx = p*256 + tid;
        int r = idx >> 4, kc = (idx & 15) << 3;
        raa[p] = *(const bf16x8*)&Hh2bf[(size_t)(row0 + r)*2048 + k0 + 128 + kc];
        rbb[p] = *(const bf16x8*)&fwT[(size_t)(col0 + r)*2048 + k0 + 128 + kc];
      }
    }
    #pragma unroll
    for (int ks = 0; ks < 4; ++ks) {
      bf16x8 a[2];
      #pragma unroll
      for (int mf = 0; mf < 2; ++mf)
        a[mf] = *(const bf16x8*)&As[(wm*32 + mf*16 + lr)*136 + ks*32 + lk*8];
      #pragma unroll
      for (int nf = 0; nf < 2; ++nf) {
        bf16x8 bfr = *(const bf16x8*)&Bs[(wn*32 + nf*16 + lr)*136 + ks*32 + lk*8];
        #pragma unroll
        for (int mf = 0; mf < 2; ++mf)
          acc[mf][nf] = __builtin_amdgcn_mfma_f32_16x16x32_bf16(a[mf], bfr, acc[mf][nf], 0, 0, 0);
      }
    }
  }
  #pragma unroll
  for (int mf = 0; mf < 2; ++mf)
    #pragma unroll
    for (int nf = 0; nf < 2; ++nf)
      #pragma unroll
      for (int r = 0; r < 4; ++r) {
        int m = row0 + wm*32 + mf*16 + lk*4 + r;
        int j = col0 + wn*32 + nf*16 + lr;
        pred0[(size_t)m*D_ + j] = acc[mf][nf][r] + fb[j];
      }
}

// K7: LN3, + head-mean (precomputed), LN4 -> out
__global__ __launch_bounds__(512) void k7_final(
    const float* __restrict__ pred0, const float* __restrict__ hmean,
    const float* __restrict__ g3, const float* __restrict__ b3,
    const float* __restrict__ g4, const float* __restrict__ b4,
    float* __restrict__ out) {
  __shared__ float red[8];
  int b = blockIdx.x, d = threadIdx.x;
  float p = pred0[(size_t)b*D_ + d];
  float s1 = bsum512(p, red);
  float s2 = bsum512(p*p, red);
  float mu = s1*(1.f/D_);
  float var = s2*(1.f/D_) - mu*mu;
  float p3 = g3[d]*((p-mu)/sqrtf(var+1e-5f)) + b3[d];
  float q = p3 + hmean[(size_t)b*D_ + d];
  s1 = bsum512(q, red);
  s2 = bsum512(q*q, red);
  mu = s1*(1.f/D_);
  var = s2*(1.f/D_) - mu*mu;
  out[(size_t)b*D_ + d] = g4[d]*((q-mu)/sqrtf(var+1e-5f)) + b4[d];
}

extern "C" void kernel_launch(void* const* d_in, const int* in_sizes, int n_in,
                              void* d_out, int out_size, void* d_ws, size_t ws_size,
                              hipStream_t stream) {
  const float* x      = (const float*)d_in[0];
  const unsigned char* amask = (const unsigned char*)d_in[1];
  const int*   order  = (const int*)d_in[2];
  const float* ndocs  = (const float*)d_in[3];
  const float* dw     = (const float*)d_in[4];
  const float* pe     = (const float*)d_in[6];
  const float* w1     = (const float*)d_in[7];
  const float* b1     = (const float*)d_in[8];
  const float* w2     = (const float*)d_in[9];
  const float* b2     = (const float*)d_in[10];
  const float* fw     = (const float*)d_in[11];
  const float* fb     = (const float*)d_in[12];
  const float* g1     = (const float*)d_in[13];
  const float* bln1   = (const float*)d_in[14];
  const float* g2     = (const float*)d_in[15];
  const float* bln2   = (const float*)d_in[16];
  const float* g3     = (const float*)d_in[17];
  const float* b3     = (const float*)d_in[18];
  const float* g4     = (const float*)d_in[19];
  const float* b4     = (const float*)d_in[20];
  float* out = (float*)d_out;

  char* ws = (char*)d_ws;
  size_t off = 0;
  u16*   x1bf   = (u16*)(ws + off);   off += (size_t)M_*D_*2;        // 125.8 MB
  float* mp     = (float*)(ws + off); off += (size_t)B_*D_*4;        // dead after k2 -> pred0 aliases
  float* pred0  = mp;
  float* mpx    = (float*)(ws + off); off += (size_t)B_*D_*4;
  float* mpW    = (float*)(ws + off); off += (size_t)B_*D_*4;
  float* hmean  = (float*)(ws + off); off += (size_t)B_*D_*4;
  float* peW    = (float*)(ws + off); off += (size_t)PE_ROWS*D_*4;
  float* cosb   = (float*)(ws + off); off += (size_t)M_*4;
  float* Zp     = (float*)(ws + off); off += (size_t)2*M_*4*4;       // 3.9 MB
  u16*   Hh2bf  = (u16*)(ws + off);   off += (size_t)B_*2048*2;      // 16.8 MB
  u16*   w1T    = (u16*)(ws + off);   off += (size_t)D_*D_*2;        // 0.5 MB
  u16*   fwT    = (u16*)(ws + off);   off += (size_t)D_*2048*2;      // 2.1 MB
  (void)ws_size; (void)in_sizes; (void)n_in; (void)out_size;

  k_tcvt<<<dim3(8, 8), 256, 0, stream>>>(w1, w1T, 512, 512);      // W_top^T
  k_tcvt<<<dim3(32, 8), 256, 0, stream>>>(fw, fwT, 2048, 512);    // fc2_w^T
  k_pew<<<PE_ROWS, 512, 0, stream>>>(pe, w1, peW);
  k1_prep<<<B_, 512, 0, stream>>>(x, order, ndocs, dw, pe, g1, bln1,
                                  x1bf, mp, mpx, cosb);
  k2_mpw<<<B_/8, 512, 0, stream>>>(mp, w1, b1, mpW);
  k4_fc1<<<dim3(M_/128, 2), 512, 0, stream>>>(x1bf, w1T, w1, w2, order, cosb,
                                              mpW, peW, Zp);
  k5_attn<<<B_/8, 512, 0, stream>>>(Zp, b2, amask, x1bf, mpx, g2, bln2,
                                    Hh2bf, hmean);
  k6_fc2<<<dim3(B_/64, 8), 256, 0, stream>>>(Hh2bf, fwT, fb, pred0);
  k7_final<<<B_, 512, 0, stream>>>(pred0, hmean, g3, b3, g4, b4, out);
}

// Round 6
// 390.333 us; speedup vs baseline: 1.1175x; 1.1175x over previous
//
#include <hip/hip_runtime.h>
#include <hip/hip_bf16.h>

#define B_ 4096
#define N_ 30
#define D_ 512
#define H_ 4
#define M_ (B_*N_)      // 122880 tokens
#define PE_ROWS 31

typedef unsigned short u16;
typedef __attribute__((ext_vector_type(8))) short bf16x8;
typedef __attribute__((ext_vector_type(4))) float f32x4;

__device__ __forceinline__ float bf2f(u16 s) { return __uint_as_float(((unsigned)s) << 16); }
__device__ __forceinline__ u16 f2bf(float f) {
  __hip_bfloat16 h = __float2bfloat16(f);
  return *reinterpret_cast<u16*>(&h);
}

// fast tanh: 1 - 2/(exp(2x)+1)
__device__ __forceinline__ float ftanh(float x) {
  float e = __expf(2.f * x);
  return 1.f - 2.f * __builtin_amdgcn_rcpf(e + 1.f);
}

// async global->LDS, 16B per lane. LDS dest = wave-uniform base + lane*16.
__device__ __forceinline__ void gll16(const void* g, void* l) {
  __builtin_amdgcn_global_load_lds(
      (const __attribute__((address_space(1))) unsigned int*)g,
      (__attribute__((address_space(3))) unsigned int*)l, 16, 0, 0);
}

// full-wave (64-lane) sum / max
__device__ __forceinline__ float wsum(float v) {
  #pragma unroll
  for (int m = 32; m >= 1; m >>= 1) v += __shfl_xor(v, m);
  return v;
}
__device__ __forceinline__ float wmax(float v) {
  #pragma unroll
  for (int m = 32; m >= 1; m >>= 1) v = fmaxf(v, __shfl_xor(v, m));
  return v;
}

// block-wide sum over 512 threads
__device__ __forceinline__ float bsum512(float v, float* red) {
  int lane = threadIdx.x & 63;
  int w = threadIdx.x >> 6;
  #pragma unroll
  for (int m = 32; m >= 1; m >>= 1) v += __shfl_xor(v, m);
  if (lane == 0) red[w] = v;
  __syncthreads();
  if (threadIdx.x < 64) {
    float t = (lane < 8) ? red[lane] : 0.0f;
    #pragma unroll
    for (int m = 4; m >= 1; m >>= 1) t += __shfl_xor(t, m);
    if (lane == 0) red[0] = t;
  }
  __syncthreads();
  float r = red[0];
  __syncthreads();
  return r;
}

// K1: wave-per-token prep (normalize -> LN1 -> +pos_emb, pools, cosine)
__global__ __launch_bounds__(512) void k1_prep(
    const float* __restrict__ x, const int* __restrict__ order,
    const float* __restrict__ ndocs, const float* __restrict__ dw,
    const float* __restrict__ pe, const float* __restrict__ g1,
    const float* __restrict__ bln1,
    u16* __restrict__ x1bf, float* __restrict__ mp, float* __restrict__ mpx,
    float* __restrict__ cosb) {
  __shared__ float lds_mp[8*512];
  __shared__ float lds_mpx[8*512];
  __shared__ float xps[32];
  int b = blockIdx.x;
  int tid = threadIdx.x;
  int wid = tid >> 6, lane = tid & 63;
  int d0 = lane * 8;
  float g[8], bl[8];
  *(float4*)&g[0]  = *(const float4*)&g1[d0];
  *(float4*)&g[4]  = *(const float4*)&g1[d0+4];
  *(float4*)&bl[0] = *(const float4*)&bln1[d0];
  *(float4*)&bl[4] = *(const float4*)&bln1[d0+4];
  float xp_reg[4][8];
  float accmp[8] = {0,0,0,0,0,0,0,0}, accmpx[8] = {0,0,0,0,0,0,0,0};
  #pragma unroll
  for (int t = 0; t < 4; ++t) {
    int n = wid + 8*t;
    if (n < N_) {
      int tok = b*N_ + n;
      float v[8];
      *(float4*)&v[0] = *(const float4*)&x[(size_t)tok*D_ + d0];
      *(float4*)&v[4] = *(const float4*)&x[(size_t)tok*D_ + d0 + 4];
      float ss = 0.f;
      #pragma unroll
      for (int i = 0; i < 8; ++i) ss += v[i]*v[i];
      ss = wsum(ss);
      float inv = 1.f / fmaxf(sqrtf(ss), 1e-8f);
      float mu = 0.f;
      #pragma unroll
      for (int i = 0; i < 8; ++i) { v[i] *= inv; mu += v[i]; }
      mu = wsum(mu) * (1.f/D_);
      float m2 = ss*inv*inv*(1.f/D_);
      float rs = 1.f / sqrtf(m2 - mu*mu + 1e-5f);
      int o = order[tok];
      float p8[8];
      *(float4*)&p8[0] = *(const float4*)&pe[(size_t)o*D_ + d0];
      *(float4*)&p8[4] = *(const float4*)&pe[(size_t)o*D_ + d0 + 4];
      float wv = dw[tok];
      float sq = 0.f;
      bf16x8 xb;
      #pragma unroll
      for (int i = 0; i < 8; ++i) {
        float x1v = g[i]*((v[i]-mu)*rs) + bl[i];
        xb[i] = (short)f2bf(x1v);
        float xpv = x1v + p8[i];
        xp_reg[t][i] = xpv;
        accmp[i]  += wv*xpv;
        accmpx[i] += wv*x1v;
        sq += xpv*xpv;
      }
      *(bf16x8*)&x1bf[(size_t)tok*D_ + d0] = xb;
      sq = wsum(sq);
      if (lane == 0) xps[n] = sq;
    }
  }
  #pragma unroll
  for (int i = 0; i < 8; i += 4) {
    *(float4*)&lds_mp[wid*512 + d0 + i]  = *(float4*)&accmp[i];
    *(float4*)&lds_mpx[wid*512 + d0 + i] = *(float4*)&accmpx[i];
  }
  __syncthreads();
  float invnd = 1.f / ndocs[b];
  float mpv[8] = {0,0,0,0,0,0,0,0}, mpxv[8] = {0,0,0,0,0,0,0,0};
  #pragma unroll
  for (int w = 0; w < 8; ++w) {
    #pragma unroll
    for (int i = 0; i < 8; i += 4) {
      float4 a = *(float4*)&lds_mp[w*512 + d0 + i];
      mpv[i+0] += a.x; mpv[i+1] += a.y; mpv[i+2] += a.z; mpv[i+3] += a.w;
      float4 c = *(float4*)&lds_mpx[w*512 + d0 + i];
      mpxv[i+0] += c.x; mpxv[i+1] += c.y; mpxv[i+2] += c.z; mpxv[i+3] += c.w;
    }
  }
  #pragma unroll
  for (int i = 0; i < 8; ++i) { mpv[i] *= invnd; mpxv[i] *= invnd; }
  if (wid == 0) {
    #pragma unroll
    for (int i = 0; i < 8; i += 4)
      *(float4*)&mp[(size_t)b*D_ + d0 + i] = *(float4*)&mpv[i];
  }
  if (wid == 1) {
    #pragma unroll
    for (int i = 0; i < 8; i += 4)
      *(float4*)&mpx[(size_t)b*D_ + d0 + i] = *(float4*)&mpxv[i];
  }
  float mn = 0.f;
  #pragma unroll
  for (int i = 0; i < 8; ++i) mn += mpv[i]*mpv[i];
  float mpn = sqrtf(wsum(mn));
  #pragma unroll
  for (int t = 0; t < 4; ++t) {
    int n = wid + 8*t;
    if (n < N_) {
      float dot = 0.f;
      #pragma unroll
      for (int i = 0; i < 8; ++i) dot += mpv[i]*xp_reg[t][i];
      dot = wsum(dot);
      if (lane == 0)
        cosb[b*N_ + n] = dot / fmaxf(mpn * sqrtf(xps[n]), 1e-8f);
    }
  }
}

// peW[p][j] = pos_emb[p] @ W_top   (31 x 512)
__global__ __launch_bounds__(512) void k_pew(
    const float* __restrict__ pe, const float* __restrict__ w1,
    float* __restrict__ peW) {
  int p = blockIdx.x, j = threadIdx.x;
  float acc = 0.f;
  for (int dd = 0; dd < D_; ++dd) acc += pe[p*D_ + dd] * w1[(size_t)dd*D_ + j];
  peW[p*D_ + j] = acc;
}

// mpW[b][j] = mp[b] @ W_mid + fc1_b1[j]
__global__ __launch_bounds__(512) void k2_mpw(
    const float* __restrict__ mp, const float* __restrict__ w1,
    const float* __restrict__ b1, float* __restrict__ mpW) {
  __shared__ float mps[8][D_];
  int j = threadIdx.x;
  int b0 = blockIdx.x * 8;
  #pragma unroll
  for (int r = 0; r < 8; ++r) mps[r][j] = mp[(size_t)(b0+r)*D_ + j];
  __syncthreads();
  float bv = b1[j];
  float acc[8] = {bv,bv,bv,bv,bv,bv,bv,bv};
  for (int dd = 0; dd < D_; ++dd) {
    float wv = w1[(size_t)(D_+dd)*D_ + j];
    #pragma unroll
    for (int r = 0; r < 8; ++r) acc[r] += mps[r][dd] * wv;
  }
  #pragma unroll
  for (int r = 0; r < 8; ++r) mpW[(size_t)(b0+r)*D_ + j] = acc[r];
}

// Tiled transpose+convert: out[j][k] = bf16(in[k][j])
__global__ __launch_bounds__(256) void k_tcvt(
    const float* __restrict__ in, u16* __restrict__ out, int Kdim, int Jdim) {
  __shared__ float tile[64][65];
  int k0 = blockIdx.x * 64, j0 = blockIdx.y * 64;
  int t = threadIdx.x;
  int tr = t >> 4, tc4 = (t & 15) * 4;
  #pragma unroll
  for (int i = 0; i < 4; ++i) {
    int k = k0 + tr + i*16;
    float4 v = *(const float4*)&in[(size_t)k*Jdim + j0 + tc4];
    tile[tr + i*16][tc4+0] = v.x;
    tile[tr + i*16][tc4+1] = v.y;
    tile[tr + i*16][tc4+2] = v.z;
    tile[tr + i*16][tc4+3] = v.w;
  }
  __syncthreads();
  #pragma unroll
  for (int i = 0; i < 4; ++i) {
    int j = tr + i*16;
    uint2 u;
    u.x = (unsigned)f2bf(tile[tc4+0][j]) | ((unsigned)f2bf(tile[tc4+1][j]) << 16);
    u.y = (unsigned)f2bf(tile[tc4+2][j]) | ((unsigned)f2bf(tile[tc4+3][j]) << 16);
    *(uint2*)&out[(size_t)(j0+j)*Kdim + k0 + tc4] = u;
  }
}

// K4 v5: m97-structure MFMA GEMM. 256 thr / 4 waves (2x2), BM=BN=128, BK=64.
// global_load_lds width-16 staging; XOR-swizzle via pre-swizzled GLOBAL source
// (linear LDS dest) + swizzled ds_read_b128 (conflict-free). Additive terms
// (mpW+peW+cos*w1_last) in acc init. Epilogue: ftanh + w2-dot -> partial Z.
__global__ __launch_bounds__(256, 3) void k4_fc1(
    const u16* __restrict__ x1bf, const u16* __restrict__ w1T,
    const float* __restrict__ w1, const float* __restrict__ w2,
    const int* __restrict__ order, const float* __restrict__ cosb,
    const float* __restrict__ mpW, const float* __restrict__ peW,
    float* __restrict__ Zp) {
  __shared__ __align__(16) u16 As[128*64];   // 16 KB, [row][64k], row=128B
  __shared__ __align__(16) u16 Bs[128*64];   // 16 KB, [col][64k]
  __shared__ float zred[2*128*4];            // 4 KB
  int tid = threadIdx.x;
  int lane = tid & 63, wid = tid >> 6;
  int col0 = blockIdx.x * 128;
  int row0 = blockIdx.y * 128;
  int wm = wid >> 1, wn = wid & 1;
  int lr = lane & 15, lk = lane >> 4;
  int srow = lane >> 3;                       // sub-row within 8-row group
  int skel = ((lane & 7) ^ srow) << 3;        // inverse-swizzled k element
  // acc init = mpW[bidx][jl] + peW[o][jl] + cs*w1_last[jl]
  float wl[4];
  #pragma unroll
  for (int nf = 0; nf < 4; ++nf)
    wl[nf] = w1[(size_t)1024*D_ + col0 + wn*64 + nf*16 + lr];
  f32x4 acc[4][4];
  #pragma unroll
  for (int mf = 0; mf < 4; ++mf) {
    #pragma unroll
    for (int r = 0; r < 4; ++r) {
      int m = row0 + wm*64 + mf*16 + lk*4 + r;
      int bidx = m / N_;
      int o = order[m];
      float cs = cosb[m];
      #pragma unroll
      for (int nf = 0; nf < 4; ++nf) {
        int jl = col0 + wn*64 + nf*16 + lr;
        acc[mf][nf][r] = mpW[(size_t)bidx*D_ + jl] + peW[o*D_ + jl] + cs*wl[nf];
      }
    }
  }
  for (int k0 = 0; k0 < D_; k0 += 64) {
    __syncthreads();                    // previous tile's reads complete
    #pragma unroll
    for (int i = 0; i < 4; ++i) {
      int rb = wid*32 + i*8;            // 8 rows per wave-load
      gll16(&x1bf[(size_t)(row0 + rb + srow)*D_ + k0 + skel], &As[rb*64]);
      gll16(&w1T [(size_t)(col0 + rb + srow)*D_ + k0 + skel], &Bs[rb*64]);
    }
    __syncthreads();                    // vmcnt(0) drained before barrier
    #pragma unroll
    for (int kk = 0; kk < 2; ++kk) {
      int kb = (kk*64 + lk*16) ^ ((lr & 7) << 4);
      bf16x8 a[4];
      #pragma unroll
      for (int mf = 0; mf < 4; ++mf)
        a[mf] = *(const bf16x8*)((const char*)As + (wm*64 + mf*16 + lr)*128 + kb);
      #pragma unroll
      for (int nf = 0; nf < 4; ++nf) {
        bf16x8 bfr = *(const bf16x8*)((const char*)Bs + (wn*64 + nf*16 + lr)*128 + kb);
        #pragma unroll
        for (int mf = 0; mf < 4; ++mf)
          acc[mf][nf] = __builtin_amdgcn_mfma_f32_16x16x32_bf16(a[mf], bfr, acc[mf][nf], 0, 0, 0);
      }
    }
  }
  // epilogue: tanh + w2-dot, reduce over 16-lane col groups
  float w2r[4][4];
  #pragma unroll
  for (int nf = 0; nf < 4; ++nf)
    *(float4*)w2r[nf] = *(const float4*)&w2[(col0 + wn*64 + nf*16 + lr)*4];
  #pragma unroll
  for (int mf = 0; mf < 4; ++mf) {
    #pragma unroll
    for (int r = 0; r < 4; ++r) {
      int rowt = wm*64 + mf*16 + lk*4 + r;
      float z0=0.f, z1=0.f, z2=0.f, z3=0.f;
      #pragma unroll
      for (int nf = 0; nf < 4; ++nf) {
        float t = ftanh(acc[mf][nf][r]);
        z0 += t * w2r[nf][0]; z1 += t * w2r[nf][1];
        z2 += t * w2r[nf][2]; z3 += t * w2r[nf][3];
      }
      #pragma unroll
      for (int msk = 1; msk <= 8; msk <<= 1) {
        z0 += __shfl_xor(z0, msk); z1 += __shfl_xor(z1, msk);
        z2 += __shfl_xor(z2, msk); z3 += __shfl_xor(z3, msk);
      }
      if (lr == 0)
        *(float4*)&zred[(wn*128 + rowt)*4] = make_float4(z0, z1, z2, z3);
    }
  }
  __syncthreads();
  if (tid < 128) {
    float4 s0 = *(float4*)&zred[tid*4];
    float4 s1 = *(float4*)&zred[(128 + tid)*4];
    *(float4*)&Zp[((size_t)blockIdx.x*M_ + row0 + tid)*4] =
        make_float4(s0.x+s1.x, s0.y+s1.y, s0.z+s1.z, s0.w+s1.w);
  }
}

// K5: wave-per-batch. Sums 4 Zp partials; in-wave softmax; bf16x8 pooling;
// LN2 -> Hh2 bf16 + head-mean f32.
__global__ __launch_bounds__(512) void k5_attn(
    const float* __restrict__ Zp, const float* __restrict__ b2,
    const unsigned char* __restrict__ amask, const u16* __restrict__ x1bf,
    const float* __restrict__ mpx, const float* __restrict__ g2,
    const float* __restrict__ bln2, u16* __restrict__ Hh2bf,
    float* __restrict__ hmean) {
  __shared__ float abuf[8][120];
  int tid = threadIdx.x;
  int wid = tid >> 6, lane = tid & 63;
  int b = blockIdx.x*8 + wid;
  bool act = lane < N_;
  int tok = b*N_ + (act ? lane : 0);
  float zz[4] = {-INFINITY, -INFINITY, -INFINITY, -INFINITY};
  if (act) {
    float4 za = *(const float4*)&Zp[(size_t)tok*4];
    float4 zb = *(const float4*)&Zp[((size_t)M_ + tok)*4];
    float4 zc = *(const float4*)&Zp[((size_t)2*M_ + tok)*4];
    float4 zd = *(const float4*)&Zp[((size_t)3*M_ + tok)*4];
    float4 bv = *(const float4*)b2;
    zz[0] = za.x+zb.x+zc.x+zd.x+bv.x; zz[1] = za.y+zb.y+zc.y+zd.y+bv.y;
    zz[2] = za.z+zb.z+zc.z+zd.z+bv.z; zz[3] = za.w+zb.w+zc.w+zd.w+bv.w;
    if (amask[tok]) { zz[0]=zz[1]=zz[2]=zz[3]=-INFINITY; }
  }
  float p[4];
  #pragma unroll
  for (int h = 0; h < 4; ++h) {
    float mx = wmax(zz[h]);
    float e = act ? __expf(zz[h] - mx) : 0.f;
    float s = wsum(e);
    p[h] = e / s;
  }
  if (act) *(float4*)&abuf[wid][lane*4] = make_float4(p[0], p[1], p[2], p[3]);
  __syncthreads();
  float hv[4][8] = {};
  const u16* xr = &x1bf[(size_t)b*N_*D_ + lane*8];
  for (int j = 0; j < N_; ++j) {
    bf16x8 xb = *(const bf16x8*)(xr + (size_t)j*D_);
    float xv[8];
    #pragma unroll
    for (int e = 0; e < 8; ++e) xv[e] = bf2f((u16)xb[e]);
    #pragma unroll
    for (int i = 0; i < 4; ++i) {
      float a = abuf[wid][i*N_ + j];
      #pragma unroll
      for (int e = 0; e < 8; ++e) hv[i][e] += a * xv[e];
    }
  }
  float mpxv[8];
  *(float4*)&mpxv[0] = *(const float4*)&mpx[(size_t)b*D_ + lane*8];
  *(float4*)&mpxv[4] = *(const float4*)&mpx[(size_t)b*D_ + lane*8 + 4];
  float s1 = 0.f, s2 = 0.f;
  #pragma unroll
  for (int i = 0; i < 4; ++i)
    #pragma unroll
    for (int e = 0; e < 8; ++e) {
      hv[i][e] += mpxv[e];
      s1 += hv[i][e];
      s2 += hv[i][e]*hv[i][e];
    }
  s1 = wsum(s1); s2 = wsum(s2);
  float mu = s1 * (1.f/2048.f);
  float var = s2 * (1.f/2048.f) - mu*mu;
  float rs = 1.f / sqrtf(var + 1e-5f);
  float hm[8] = {0,0,0,0,0,0,0,0};
  #pragma unroll
  for (int i = 0; i < 4; ++i) {
    int idx = i*D_ + lane*8;
    float gg[8], bb[8];
    *(float4*)&gg[0] = *(const float4*)&g2[idx];
    *(float4*)&gg[4] = *(const float4*)&g2[idx+4];
    *(float4*)&bb[0] = *(const float4*)&bln2[idx];
    *(float4*)&bb[4] = *(const float4*)&bln2[idx+4];
    bf16x8 ob;
    #pragma unroll
    for (int e = 0; e < 8; ++e) {
      float v = gg[e]*((hv[i][e]-mu)*rs) + bb[e];
      hm[e] += v;
      ob[e] = (short)f2bf(v);
    }
    *(bf16x8*)&Hh2bf[(size_t)b*2048 + idx] = ob;
  }
  #pragma unroll
  for (int e = 0; e < 8; ++e) hm[e] *= 0.25f;
  *(float4*)&hmean[(size_t)b*D_ + lane*8]     = *(float4*)&hm[0];
  *(float4*)&hmean[(size_t)b*D_ + lane*8 + 4] = *(float4*)&hm[4];
}

// K6 v3: same m97 template. 64x64 tile, BK=64, split-K=2 (blockIdx.z).
// grid (8,64,2)=1024 blocks -> 4 blocks/CU. Writes partial pred (no bias).
__global__ __launch_bounds__(256, 3) void k6_fc2(
    const u16* __restrict__ Hh2bf, const u16* __restrict__ fwT,
    float* __restrict__ pred_p) {
  __shared__ __align__(16) u16 As[64*64];   // 8 KB
  __shared__ __align__(16) u16 Bs[64*64];   // 8 KB
  int tid = threadIdx.x;
  int lane = tid & 63, wid = tid >> 6;
  int col0 = blockIdx.x * 64;
  int row0 = blockIdx.y * 64;
  int kbase = blockIdx.z * 1024;
  int wm = wid >> 1, wn = wid & 1;
  int lr = lane & 15, lk = lane >> 4;
  int srow = lane >> 3;
  int skel = ((lane & 7) ^ srow) << 3;
  f32x4 acc[2][2] = {};
  for (int k0 = kbase; k0 < kbase + 1024; k0 += 64) {
    __syncthreads();
    #pragma unroll
    for (int i = 0; i < 2; ++i) {
      int rb = wid*16 + i*8;
      gll16(&Hh2bf[(size_t)(row0 + rb + srow)*2048 + k0 + skel], &As[rb*64]);
      gll16(&fwT  [(size_t)(col0 + rb + srow)*2048 + k0 + skel], &Bs[rb*64]);
    }
    __syncthreads();
    #pragma unroll
    for (int kk = 0; kk < 2; ++kk) {
      int kb = (kk*64 + lk*16) ^ ((lr & 7) << 4);
      bf16x8 a[2];
      #pragma unroll
      for (int mf = 0; mf < 2; ++mf)
        a[mf] = *(const bf16x8*)((const char*)As + (wm*32 + mf*16 + lr)*128 + kb);
      #pragma unroll
      for (int nf = 0; nf < 2; ++nf) {
        bf16x8 bfr = *(const bf16x8*)((const char*)Bs + (wn*32 + nf*16 + lr)*128 + kb);
        #pragma unroll
        for (int mf = 0; mf < 2; ++mf)
          acc[mf][nf] = __builtin_amdgcn_mfma_f32_16x16x32_bf16(a[mf], bfr, acc[mf][nf], 0, 0, 0);
      }
    }
  }
  float* dst = pred_p + (size_t)blockIdx.z * B_ * D_;
  #pragma unroll
  for (int mf = 0; mf < 2; ++mf)
    #pragma unroll
    for (int nf = 0; nf < 2; ++nf)
      #pragma unroll
      for (int r = 0; r < 4; ++r) {
        int m = row0 + wm*32 + mf*16 + lk*4 + r;
        int j = col0 + wn*32 + nf*16 + lr;
        dst[(size_t)m*D_ + j] = acc[mf][nf][r];
      }
}

// K7: combine split-K + fb, LN3, + head-mean, LN4 -> out
__global__ __launch_bounds__(512) void k7_final(
    const float* __restrict__ pred_p, const float* __restrict__ hmean,
    const float* __restrict__ fb,
    const float* __restrict__ g3, const float* __restrict__ b3,
    const float* __restrict__ g4, const float* __restrict__ b4,
    float* __restrict__ out) {
  __shared__ float red[8];
  int b = blockIdx.x, d = threadIdx.x;
  float p = pred_p[(size_t)b*D_ + d] + pred_p[(size_t)B_*D_ + (size_t)b*D_ + d]
          + fb[d];
  float s1 = bsum512(p, red);
  float s2 = bsum512(p*p, red);
  float mu = s1*(1.f/D_);
  float var = s2*(1.f/D_) - mu*mu;
  float p3 = g3[d]*((p-mu)/sqrtf(var+1e-5f)) + b3[d];
  float q = p3 + hmean[(size_t)b*D_ + d];
  s1 = bsum512(q, red);
  s2 = bsum512(q*q, red);
  mu = s1*(1.f/D_);
  var = s2*(1.f/D_) - mu*mu;
  out[(size_t)b*D_ + d] = g4[d]*((q-mu)/sqrtf(var+1e-5f)) + b4[d];
}

extern "C" void kernel_launch(void* const* d_in, const int* in_sizes, int n_in,
                              void* d_out, int out_size, void* d_ws, size_t ws_size,
                              hipStream_t stream) {
  const float* x      = (const float*)d_in[0];
  const unsigned char* amask = (const unsigned char*)d_in[1];
  const int*   order  = (const int*)d_in[2];
  const float* ndocs  = (const float*)d_in[3];
  const float* dw     = (const float*)d_in[4];
  const float* pe     = (const float*)d_in[6];
  const float* w1     = (const float*)d_in[7];
  const float* b1     = (const float*)d_in[8];
  const float* w2     = (const float*)d_in[9];
  const float* b2     = (const float*)d_in[10];
  const float* fw     = (const float*)d_in[11];
  const float* fb     = (const float*)d_in[12];
  const float* g1     = (const float*)d_in[13];
  const float* bln1   = (const float*)d_in[14];
  const float* g2     = (const float*)d_in[15];
  const float* bln2   = (const float*)d_in[16];
  const float* g3     = (const float*)d_in[17];
  const float* b3     = (const float*)d_in[18];
  const float* g4     = (const float*)d_in[19];
  const float* b4     = (const float*)d_in[20];
  float* out = (float*)d_out;

  char* ws = (char*)d_ws;
  size_t off = 0;
  u16*   x1bf   = (u16*)(ws + off);   off += (size_t)M_*D_*2;        // 125.8 MB
  float* mp     = (float*)(ws + off); off += (size_t)B_*D_*4;
  float* mpx    = (float*)(ws + off); off += (size_t)B_*D_*4;
  float* mpW    = (float*)(ws + off); off += (size_t)B_*D_*4;
  float* hmean  = (float*)(ws + off); off += (size_t)B_*D_*4;
  float* peW    = (float*)(ws + off); off += (size_t)PE_ROWS*D_*4;
  float* cosb   = (float*)(ws + off); off += (size_t)M_*4;
  float* Zp     = (float*)(ws + off); off += (size_t)4*M_*4*4;       // 7.9 MB
  float* pred_p = (float*)(ws + off); off += (size_t)2*B_*D_*4;      // 16.8 MB
  u16*   Hh2bf  = (u16*)(ws + off);   off += (size_t)B_*2048*2;      // 16.8 MB
  u16*   w1T    = (u16*)(ws + off);   off += (size_t)D_*D_*2;        // 0.5 MB
  u16*   fwT    = (u16*)(ws + off);   off += (size_t)D_*2048*2;      // 2.1 MB
  (void)ws_size; (void)in_sizes; (void)n_in; (void)out_size;

  k_tcvt<<<dim3(8, 8), 256, 0, stream>>>(w1, w1T, 512, 512);      // W_top^T
  k_tcvt<<<dim3(32, 8), 256, 0, stream>>>(fw, fwT, 2048, 512);    // fc2_w^T
  k_pew<<<PE_ROWS, 512, 0, stream>>>(pe, w1, peW);
  k1_prep<<<B_, 512, 0, stream>>>(x, order, ndocs, dw, pe, g1, bln1,
                                  x1bf, mp, mpx, cosb);
  k2_mpw<<<B_/8, 512, 0, stream>>>(mp, w1, b1, mpW);
  k4_fc1<<<dim3(4, M_/128), 256, 0, stream>>>(x1bf, w1T, w1, w2, order, cosb,
                                              mpW, peW, Zp);
  k5_attn<<<B_/8, 512, 0, stream>>>(Zp, b2, amask, x1bf, mpx, g2, bln2,
                                    Hh2bf, hmean);
  k6_fc2<<<dim3(8, 64, 2), 256, 0, stream>>>(Hh2bf, fwT, pred_p);
  k7_final<<<B_, 512, 0, stream>>>(pred_p, hmean, fb, g3, b3, g4, b4, out);
}